// Round 1
// baseline (506.904 us; speedup 1.0000x reference)
//
#include <hip/hip_runtime.h>

#define N_GRAPHS    8
#define EDGES_PER_G 2048
#define NN          8192
#define EE          16384
#define IN_DIM      10
#define EDGE_DIM    9
#define HID         64
#define OUT_DIM     3
#define TT          5
#define EPSN        1e-6f

typedef float f32x4 __attribute__((ext_vector_type(4)));
typedef short bf16x8s __attribute__((ext_vector_type(8)));

union BF8 { __bf16 h[8]; bf16x8s v; };

__device__ inline void mfma16x16x32(bf16x8s a, bf16x8s b, f32x4& c) {
  // D==C accumulate in place; "+v" ties them so no illegal overlap with A/B.
  asm("v_mfma_f32_16x16x32_bf16 %0, %1, %2, %0" : "+v"(c) : "v"(a), "v"(b));
}

// ---------------- per-graph edge_attr stats (block g reduces its 2048 edges) --------
__global__ void k_stats(const float* __restrict__ ear, float* __restrict__ meanb,
                        float* __restrict__ invstd) {
  __shared__ float ssum[EDGE_DIM], ssq[EDGE_DIM];
  int g = blockIdx.x;
  if (threadIdx.x < EDGE_DIM) { ssum[threadIdx.x] = 0.f; ssq[threadIdx.x] = 0.f; }
  __syncthreads();
  float ls[EDGE_DIM], lq[EDGE_DIM];
#pragma unroll
  for (int d = 0; d < EDGE_DIM; ++d) { ls[d] = 0.f; lq[d] = 0.f; }
  for (int e = threadIdx.x; e < EDGES_PER_G; e += blockDim.x) {
    const float* row = ear + (size_t)(g * EDGES_PER_G + e) * EDGE_DIM;
#pragma unroll
    for (int d = 0; d < EDGE_DIM; ++d) { float x = row[d]; ls[d] += x; lq[d] += x * x; }
  }
#pragma unroll
  for (int d = 0; d < EDGE_DIM; ++d) { atomicAdd(&ssum[d], ls[d]); atomicAdd(&ssq[d], lq[d]); }
  __syncthreads();
  if (threadIdx.x < EDGE_DIM) {
    float m  = ssum[threadIdx.x] * (1.0f / EDGES_PER_G);
    float mq = ssq[threadIdx.x] * (1.0f / EDGES_PER_G);
    float var = fmaxf(mq - m * m, 0.f);
    meanb[g * EDGE_DIM + threadIdx.x]  = m;
    invstd[g * EDGE_DIM + threadIdx.x] = 1.f / (sqrtf(var) + EPSN);
  }
}

__global__ void k_norm(const float* __restrict__ ear, const float* __restrict__ meanb,
                       const float* __restrict__ invstd, float* __restrict__ ea) {
  int i = blockIdx.x * blockDim.x + threadIdx.x;
  if (i >= EE * EDGE_DIM) return;
  int e = i / EDGE_DIM;
  int d = i - e * EDGE_DIM;
  int g = e >> 11;               // edges are block-structured by construction
  ea[i] = (ear[i] - meanb[g * EDGE_DIM + d]) * invstd[g * EDGE_DIM + d];
}

__global__ void k_deg(const int* __restrict__ dst, float* __restrict__ degf) {
  int e = blockIdx.x * blockDim.x + threadIdx.x;
  if (e < EE) atomicAdd(&degf[dst[e]], 1.f);
}

__global__ void k_invdeg(const float* __restrict__ degf, float* __restrict__ invdeg) {
  int n = blockIdx.x * blockDim.x + threadIdx.x;
  if (n < NN) invdeg[n] = 1.f / fmaxf(degf[n], 1.f);
}

// ---------------- lift MLP: v = relu(x@w1+b1)@w2+b2 ----------------
__global__ __launch_bounds__(256) void k_lift(const float* __restrict__ x,
    const float* __restrict__ w1, const float* __restrict__ b1,
    const float* __restrict__ w2, const float* __restrict__ b2,
    float* __restrict__ v) {
  __shared__ float h1s[4][HID];
  int g = threadIdx.x >> 6, lane = threadIdx.x & 63;
  int n = blockIdx.x * 4 + g;
  const float* xr = x + n * IN_DIM;
  float a = b1[lane];
#pragma unroll
  for (int d = 0; d < IN_DIM; ++d) a += xr[d] * w1[d * HID + lane];
  h1s[g][lane] = fmaxf(a, 0.f);
  __syncthreads();
  float o = b2[lane];
#pragma unroll
  for (int h = 0; h < HID; ++h) o += h1s[g][h] * w2[h * HID + lane];
  v[n * HID + lane] = o;
}

// ---------------- convert k_w3 (+ k_b3 as c=64 row) to bf16 ----------------
__global__ void k_bprep(const float* __restrict__ kw3, const float* __restrict__ kb3,
                        unsigned short* __restrict__ Bbf) {
  const int total = TT * 65 * 4096;
  for (int i = blockIdx.x * blockDim.x + threadIdx.x; i < total; i += gridDim.x * blockDim.x) {
    int x    = i & 4095;
    int call = i >> 12;          // t*65 + c
    int t = call / 65;
    int c = call - t * 65;
    float val = (c < 64) ? kw3[(size_t)(t * 64 + c) * 4096 + x] : kb3[t * 4096 + x];
    union { __bf16 h; unsigned short s; } u;
    u.h = (__bf16)val;
    Bbf[i] = u.s;
  }
}

// ---------------- per-layer edge MLP: h2 = relu(relu(ea@w1+b1)@w2+b2) ----------------
__global__ __launch_bounds__(256) void k_edgemlp(const float* __restrict__ ea,
    const float* __restrict__ w1, const float* __restrict__ b1,
    const float* __restrict__ w2, const float* __restrict__ b2,
    float* __restrict__ h2) {
  __shared__ float h1s[4][HID];
  int g = threadIdx.x >> 6, lane = threadIdx.x & 63;
  int e = blockIdx.x * 4 + g;
  const float* er = ea + e * EDGE_DIM;
  float a = b1[lane];
#pragma unroll
  for (int d = 0; d < EDGE_DIM; ++d) a += er[d] * w1[d * HID + lane];
  h1s[g][lane] = fmaxf(a, 0.f);
  __syncthreads();
  float o = b2[lane];
#pragma unroll
  for (int h = 0; h < HID; ++h) o += h1s[g][h] * w2[h * HID + lane];
  h2[e * HID + lane] = fmaxf(o, 0.f);
}

// ---------------- the big one: Msg[E,64] = A[E,4160] @ B[4160,64], scatter into aggr -
// A[e, c*64+j] = h2[e,c] * v[src[e], j]   (c==64 row: h2 == 1 -> bias b3)
// wave tile: 32 edges x 64 outputs; split-K=2; grid = 128 edge-blocks * 2 = 256 blocks.
__global__ __launch_bounds__(256) void k_msg(const float* __restrict__ v,
    const float* __restrict__ h2, const unsigned short* __restrict__ Bt,
    const int* __restrict__ src, const int* __restrict__ dst,
    float* __restrict__ aggr) {
  int kchunk = blockIdx.x & 1;
  int ebb    = (blockIdx.x >> 1) * 128;
  int w    = threadIdx.x >> 6;
  int lane = threadIdx.x & 63;
  int n15  = lane & 15;
  int q    = lane >> 4;
  int ebase = ebb + w * 32;
  int c0 = kchunk ? 33 : 0;
  int c1 = kchunk ? 65 : 33;

  int e_m[2];
  float4 vs[2][2][2];   // [m-tile][k-step s][half]: v[src[e]][s*32 + q*8 .. +8]
#pragma unroll
  for (int mt = 0; mt < 2; ++mt) {
    int e = ebase + mt * 16 + n15;
    e_m[mt] = e;
    const float4* vr = (const float4*)(v + (size_t)src[e] * HID);
    int f0 = q * 2;
    vs[mt][0][0] = vr[f0];     vs[mt][0][1] = vr[f0 + 1];
    vs[mt][1][0] = vr[8 + f0]; vs[mt][1][1] = vr[8 + f0 + 1];
  }

  f32x4 acc[2][4];
#pragma unroll
  for (int mt = 0; mt < 2; ++mt)
#pragma unroll
    for (int nt = 0; nt < 4; ++nt) acc[mt][nt] = (f32x4)0.0f;

  for (int c = c0; c < c1; ++c) {
    bf16x8s afr[2][2];
#pragma unroll
    for (int mt = 0; mt < 2; ++mt) {
      float hc = (c < 64) ? h2[(size_t)e_m[mt] * HID + c] : 1.0f;
#pragma unroll
      for (int s = 0; s < 2; ++s) {
        BF8 u;
        float4 pa = vs[mt][s][0], pb = vs[mt][s][1];
        u.h[0] = (__bf16)(hc * pa.x); u.h[1] = (__bf16)(hc * pa.y);
        u.h[2] = (__bf16)(hc * pa.z); u.h[3] = (__bf16)(hc * pa.w);
        u.h[4] = (__bf16)(hc * pb.x); u.h[5] = (__bf16)(hc * pb.y);
        u.h[6] = (__bf16)(hc * pb.z); u.h[7] = (__bf16)(hc * pb.w);
        afr[mt][s] = u.v;
      }
    }
    const unsigned short* Bc = Bt + (size_t)c * 4096;
#pragma unroll
    for (int s = 0; s < 2; ++s) {
      bf16x8s bfr[4];
#pragma unroll
      for (int nt = 0; nt < 4; ++nt)
        bfr[nt] = *(const bf16x8s*)(Bc + (nt * 16 + n15) * 64 + s * 32 + q * 8);
#pragma unroll
      for (int mt = 0; mt < 2; ++mt)
#pragma unroll
        for (int nt = 0; nt < 4; ++nt)
          mfma16x16x32(afr[mt][s], bfr[nt], acc[mt][nt]);
    }
  }

  // epilogue: C/D layout row = q*4+r (edge), col = n15 (i); scatter-add by dst
#pragma unroll
  for (int mt = 0; mt < 2; ++mt) {
#pragma unroll
    for (int r = 0; r < 4; ++r) {
      int e = ebase + mt * 16 + q * 4 + r;
      int d = dst[e];
      float* ag = aggr + (size_t)d * HID;
#pragma unroll
      for (int nt = 0; nt < 4; ++nt)
        atomicAdd(ag + nt * 16 + n15, acc[mt][nt][r]);
    }
  }
}

// ---------------- root update: v = relu(v@rw + rb + aggr/deg) (in place) ----------------
__global__ __launch_bounds__(256) void k_update(float* __restrict__ v,
    const float* __restrict__ rw, const float* __restrict__ rb,
    const float* __restrict__ aggr, const float* __restrict__ invdeg) {
  __shared__ float sv[4][HID];
  int g = threadIdx.x >> 6, lane = threadIdx.x & 63;
  int n = blockIdx.x * 4 + g;
  sv[g][lane] = v[n * HID + lane];
  __syncthreads();
  float o = rb[lane] + aggr[n * HID + lane] * invdeg[n];
#pragma unroll
  for (int h = 0; h < HID; ++h) o += sv[g][h] * rw[h * HID + lane];
  v[n * HID + lane] = fmaxf(o, 0.f);
}

// ---------------- proj MLP: out = relu(v@w1+b1)@w2+b2 ----------------
__global__ __launch_bounds__(256) void k_proj(const float* __restrict__ v,
    const float* __restrict__ w1, const float* __restrict__ b1,
    const float* __restrict__ w2, const float* __restrict__ b2,
    float* __restrict__ out) {
  __shared__ float h1s[4][HID];
  int g = threadIdx.x >> 6, lane = threadIdx.x & 63;
  int n = blockIdx.x * 4 + g;
  float a = b1[lane];
#pragma unroll
  for (int h = 0; h < HID; ++h) a += v[n * HID + h] * w1[h * HID + lane];
  h1s[g][lane] = fmaxf(a, 0.f);
  __syncthreads();
  if (lane < OUT_DIM) {
    float o = b2[lane];
#pragma unroll
    for (int h = 0; h < HID; ++h) o += h1s[g][h] * w2[h * OUT_DIM + lane];
    out[n * OUT_DIM + lane] = o;
  }
}

extern "C" void kernel_launch(void* const* d_in, const int* in_sizes, int n_in,
                              void* d_out, int out_size, void* d_ws, size_t ws_size,
                              hipStream_t stream) {
  const float* x        = (const float*)d_in[0];
  const float* ear      = (const float*)d_in[1];
  const float* lift_w1  = (const float*)d_in[2];
  const float* lift_b1  = (const float*)d_in[3];
  const float* lift_w2  = (const float*)d_in[4];
  const float* lift_b2  = (const float*)d_in[5];
  const float* root_w   = (const float*)d_in[6];
  const float* root_b   = (const float*)d_in[7];
  const float* kw1      = (const float*)d_in[8];
  const float* kb1      = (const float*)d_in[9];
  const float* kw2      = (const float*)d_in[10];
  const float* kb2      = (const float*)d_in[11];
  const float* kw3      = (const float*)d_in[12];
  const float* kb3      = (const float*)d_in[13];
  const float* pw1      = (const float*)d_in[14];
  const float* pb1      = (const float*)d_in[15];
  const float* pw2      = (const float*)d_in[16];
  const float* pb2      = (const float*)d_in[17];
  const int* edge_index = (const int*)d_in[18];
  const int* src = edge_index;
  const int* dst = edge_index + EE;
  float* out = (float*)d_out;

  float* ws      = (float*)d_ws;
  float* ea      = ws;                         // E*9
  float* h2buf   = ea + EE * EDGE_DIM;         // E*64
  float* vbuf    = h2buf + EE * HID;           // N*64
  float* aggr    = vbuf + NN * HID;            // N*64
  float* meanb   = aggr + NN * HID;            // 72
  float* invstd  = meanb + 72;                 // 72
  float* degf    = invstd + 72;                // N
  float* invdeg  = degf + NN;                  // N
  unsigned short* Bbf = (unsigned short*)(invdeg + NN);  // 5*65*4096 bf16 (16B aligned)

  hipMemsetAsync(degf, 0, NN * sizeof(float), stream);
  k_stats<<<N_GRAPHS, 256, 0, stream>>>(ear, meanb, invstd);
  k_norm<<<(EE * EDGE_DIM + 255) / 256, 256, 0, stream>>>(ear, meanb, invstd, ea);
  k_deg<<<EE / 256, 256, 0, stream>>>(dst, degf);
  k_invdeg<<<NN / 256, 256, 0, stream>>>(degf, invdeg);
  k_lift<<<NN / 4, 256, 0, stream>>>(x, lift_w1, lift_b1, lift_w2, lift_b2, vbuf);
  k_bprep<<<1024, 256, 0, stream>>>(kw3, kb3, Bbf);

  for (int t = 0; t < TT; ++t) {
    k_edgemlp<<<EE / 4, 256, 0, stream>>>(ea,
        kw1 + t * EDGE_DIM * HID, kb1 + t * HID,
        kw2 + t * HID * HID, kb2 + t * HID, h2buf);
    hipMemsetAsync(aggr, 0, (size_t)NN * HID * sizeof(float), stream);
    k_msg<<<256, 256, 0, stream>>>(vbuf, h2buf, Bbf + (size_t)t * 65 * 4096, src, dst, aggr);
    k_update<<<NN / 4, 256, 0, stream>>>(vbuf,
        root_w + t * HID * HID, root_b + t * HID, aggr, invdeg);
  }
  k_proj<<<NN / 4, 256, 0, stream>>>(vbuf, pw1, pb1, pw2, pb2, out);
}

// Round 3
// 499.604 us; speedup vs baseline: 1.0146x; 1.0146x over previous
//
#include <hip/hip_runtime.h>

#define N_GRAPHS    8
#define EDGES_PER_G 2048
#define NN          8192
#define EE          16384
#define IN_DIM      10
#define EDGE_DIM    9
#define HID         64
#define OUT_DIM     3
#define TT          5
#define EPSN        1e-6f

typedef float f32x4 __attribute__((ext_vector_type(4)));
typedef short bf16x8s __attribute__((ext_vector_type(8)));

union BF8 { __bf16 h[8]; bf16x8s v; };

// ---------------- fused edge MLP body (normalization folded in) ----------------
// h2[e] = relu(relu(norm(ear[e]) @ w1 + b1) @ w2 + b2)
__device__ inline void edgemlp_body(int e, int lane, int g, float (*sh)[HID],
    const float* __restrict__ ear, const float* __restrict__ meanb,
    const float* __restrict__ invstd,
    const float* __restrict__ w1, const float* __restrict__ b1,
    const float* __restrict__ w2, const float* __restrict__ b2,
    float* __restrict__ h2) {
  int gg = e >> 11;                        // 2048 edges per graph
  const float* er = ear + (size_t)e * EDGE_DIM;
  const float* mb = meanb + gg * EDGE_DIM;
  const float* is = invstd + gg * EDGE_DIM;
  float xn[EDGE_DIM];
#pragma unroll
  for (int d = 0; d < EDGE_DIM; ++d) xn[d] = (er[d] - mb[d]) * is[d];
  float a = b1[lane];
#pragma unroll
  for (int d = 0; d < EDGE_DIM; ++d) a += xn[d] * w1[d * HID + lane];
  sh[g][lane] = fmaxf(a, 0.f);
  __syncthreads();
  float o = b2[lane];
#pragma unroll
  for (int h = 0; h < HID; ++h) o += sh[g][h] * w2[h * HID + lane];
  h2[(size_t)e * HID + lane] = fmaxf(o, 0.f);
}

// ---------------- preamble: lift | bprep | deg | stats (block-partitioned) -------
__global__ __launch_bounds__(256) void k_pre(
    const float* __restrict__ x,
    const float* __restrict__ lw1, const float* __restrict__ lb1,
    const float* __restrict__ lw2, const float* __restrict__ lb2,
    float* __restrict__ v,
    const float* __restrict__ kw3, const float* __restrict__ kb3,
    unsigned short* __restrict__ Bbf,
    const int* __restrict__ dst, float* __restrict__ degf,
    const float* __restrict__ ear, float* __restrict__ meanb,
    float* __restrict__ invstd) {
  __shared__ float sh[4][HID];
  int b = blockIdx.x;
  int g = threadIdx.x >> 6, lane = threadIdx.x & 63;
  if (b < NN / 4) {
    // ---- lift MLP ----
    int n = b * 4 + g;
    const float* xr = x + n * IN_DIM;
    float a = lb1[lane];
#pragma unroll
    for (int d = 0; d < IN_DIM; ++d) a += xr[d] * lw1[d * HID + lane];
    sh[g][lane] = fmaxf(a, 0.f);
    __syncthreads();
    float o = lb2[lane];
#pragma unroll
    for (int h = 0; h < HID; ++h) o += sh[g][h] * lw2[h * HID + lane];
    v[n * HID + lane] = o;
  } else if (b < NN / 4 + 1024) {
    // ---- bprep: kw3 (+kb3 as row 64) -> bf16, layout [t][c][i*64+j] ----
    const int total = TT * 65 * 4096;
    for (int i = (b - NN / 4) * 256 + (int)threadIdx.x; i < total; i += 1024 * 256) {
      int xx = i & 4095;
      int call = i >> 12;
      int t = call / 65;
      int c = call - t * 65;
      float val = (c < 64) ? kw3[(size_t)(t * 64 + c) * 4096 + xx] : kb3[(size_t)t * 4096 + xx];
      union { __bf16 h; unsigned short s; } u;
      u.h = (__bf16)val;
      Bbf[i] = u.s;
    }
  } else if (b < NN / 4 + 1024 + EE / 256) {
    // ---- deg histogram ----
    int e = (b - (NN / 4 + 1024)) * 256 + threadIdx.x;
    atomicAdd(&degf[dst[e]], 1.f);
  } else {
    // ---- per-graph edge_attr stats ----
    int gg = b - (NN / 4 + 1024 + EE / 256);
    float* ssum = &sh[0][0];
    float* ssq  = &sh[1][0];
    if (threadIdx.x < EDGE_DIM) { ssum[threadIdx.x] = 0.f; ssq[threadIdx.x] = 0.f; }
    __syncthreads();
    float ls[EDGE_DIM], lq[EDGE_DIM];
#pragma unroll
    for (int d = 0; d < EDGE_DIM; ++d) { ls[d] = 0.f; lq[d] = 0.f; }
    for (int e = threadIdx.x; e < EDGES_PER_G; e += blockDim.x) {
      const float* row = ear + (size_t)(gg * EDGES_PER_G + e) * EDGE_DIM;
#pragma unroll
      for (int d = 0; d < EDGE_DIM; ++d) { float xv = row[d]; ls[d] += xv; lq[d] += xv * xv; }
    }
#pragma unroll
    for (int d = 0; d < EDGE_DIM; ++d) { atomicAdd(&ssum[d], ls[d]); atomicAdd(&ssq[d], lq[d]); }
    __syncthreads();
    if (threadIdx.x < EDGE_DIM) {
      float m  = ssum[threadIdx.x] * (1.0f / EDGES_PER_G);
      float mq = ssq[threadIdx.x] * (1.0f / EDGES_PER_G);
      float var = fmaxf(mq - m * m, 0.f);
      meanb[gg * EDGE_DIM + threadIdx.x]  = m;
      invstd[gg * EDGE_DIM + threadIdx.x] = 1.f / (sqrtf(var) + EPSN);
    }
  }
}

// ---------------- standalone edge MLP (layer 0) ----------------
__global__ __launch_bounds__(256) void k_em(const float* __restrict__ ear,
    const float* __restrict__ meanb, const float* __restrict__ invstd,
    const float* __restrict__ w1, const float* __restrict__ b1,
    const float* __restrict__ w2, const float* __restrict__ b2,
    float* __restrict__ h2) {
  __shared__ float sh[4][HID];
  int g = threadIdx.x >> 6, lane = threadIdx.x & 63;
  int e = blockIdx.x * 4 + g;
  edgemlp_body(e, lane, g, sh, ear, meanb, invstd, w1, b1, w2, b2, h2);
}

// ---------------- msg GEMM: Msg[E,64] = A[E,4160] @ B[4160,64], scatter by dst ----
// A[e, c*64+j] = h2[e,c] * v[src[e], j]  (row c==64: h2==1 -> bias b3)
// wave tile 32 edges x 64 out; split-K=4 over c: chunk k owns rows [16k,16k+16),
// chunk 3 additionally does the bias row (c=64). Builtin MFMA (compiler handles
// hazards), compile-time 16-trip loop with unroll-4 for load batching.
__global__ __launch_bounds__(256) void k_msg(const float* __restrict__ v,
    const float* __restrict__ h2, const unsigned short* __restrict__ Bt,
    const int* __restrict__ src, const int* __restrict__ dst,
    float* __restrict__ aggr) {
  int kchunk = blockIdx.x & 3;
  int ebb    = (blockIdx.x >> 2) * 128;
  int w    = threadIdx.x >> 6;
  int lane = threadIdx.x & 63;
  int n15  = lane & 15;
  int q    = lane >> 4;
  int ebase = ebb + w * 32;

  int e_m[2];
  float4 vs[2][2][2];   // [m-tile][k-step s][half]: v[src[e]][s*32 + q*8 .. +8]
#pragma unroll
  for (int mt = 0; mt < 2; ++mt) {
    int e = ebase + mt * 16 + n15;
    e_m[mt] = e;
    const float4* vr = (const float4*)(v + (size_t)src[e] * HID);
    int f0 = q * 2;
    vs[mt][0][0] = vr[f0];     vs[mt][0][1] = vr[f0 + 1];
    vs[mt][1][0] = vr[8 + f0]; vs[mt][1][1] = vr[8 + f0 + 1];
  }

  f32x4 acc[2][4];
#pragma unroll
  for (int mt = 0; mt < 2; ++mt)
#pragma unroll
    for (int nt = 0; nt < 4; ++nt) acc[mt][nt] = (f32x4)0.0f;

  int c0 = kchunk * 16;
  const unsigned short* Bp = Bt + (size_t)c0 * 4096 + (size_t)n15 * 64 + q * 8;
  const float* h0p = h2 + (size_t)e_m[0] * HID + c0;
  const float* h1p = h2 + (size_t)e_m[1] * HID + c0;

#pragma unroll 4
  for (int cc = 0; cc < 16; ++cc) {
    float hh[2];
    hh[0] = h0p[cc];
    hh[1] = h1p[cc];
    const unsigned short* Bc = Bp + (size_t)cc * 4096;
    bf16x8s bfr[2][4];
#pragma unroll
    for (int s = 0; s < 2; ++s)
#pragma unroll
      for (int nt = 0; nt < 4; ++nt)
        bfr[s][nt] = *(const bf16x8s*)(Bc + nt * 1024 + s * 32);
    bf16x8s afr[2][2];
#pragma unroll
    for (int mt = 0; mt < 2; ++mt) {
      float hc = hh[mt];
#pragma unroll
      for (int s = 0; s < 2; ++s) {
        BF8 u;
        float4 pa = vs[mt][s][0], pb = vs[mt][s][1];
        u.h[0] = (__bf16)(hc * pa.x); u.h[1] = (__bf16)(hc * pa.y);
        u.h[2] = (__bf16)(hc * pa.z); u.h[3] = (__bf16)(hc * pa.w);
        u.h[4] = (__bf16)(hc * pb.x); u.h[5] = (__bf16)(hc * pb.y);
        u.h[6] = (__bf16)(hc * pb.z); u.h[7] = (__bf16)(hc * pb.w);
        afr[mt][s] = u.v;
      }
    }
#pragma unroll
    for (int s = 0; s < 2; ++s)
#pragma unroll
      for (int mt = 0; mt < 2; ++mt)
#pragma unroll
        for (int nt = 0; nt < 4; ++nt)
          acc[mt][nt] = __builtin_amdgcn_mfma_f32_16x16x32_bf16(
              afr[mt][s], bfr[s][nt], acc[mt][nt], 0, 0, 0);
  }

  if (kchunk == 3) {
    // bias row c = 64 (h == 1)
    const unsigned short* Bc = Bt + (size_t)64 * 4096 + (size_t)n15 * 64 + q * 8;
    bf16x8s bfr[2][4];
#pragma unroll
    for (int s = 0; s < 2; ++s)
#pragma unroll
      for (int nt = 0; nt < 4; ++nt)
        bfr[s][nt] = *(const bf16x8s*)(Bc + nt * 1024 + s * 32);
    bf16x8s afr[2][2];
#pragma unroll
    for (int mt = 0; mt < 2; ++mt)
#pragma unroll
      for (int s = 0; s < 2; ++s) {
        BF8 u;
        float4 pa = vs[mt][s][0], pb = vs[mt][s][1];
        u.h[0] = (__bf16)pa.x; u.h[1] = (__bf16)pa.y;
        u.h[2] = (__bf16)pa.z; u.h[3] = (__bf16)pa.w;
        u.h[4] = (__bf16)pb.x; u.h[5] = (__bf16)pb.y;
        u.h[6] = (__bf16)pb.z; u.h[7] = (__bf16)pb.w;
        afr[mt][s] = u.v;
      }
#pragma unroll
    for (int s = 0; s < 2; ++s)
#pragma unroll
      for (int mt = 0; mt < 2; ++mt)
#pragma unroll
        for (int nt = 0; nt < 4; ++nt)
          acc[mt][nt] = __builtin_amdgcn_mfma_f32_16x16x32_bf16(
              afr[mt][s], bfr[s][nt], acc[mt][nt], 0, 0, 0);
  }

  // epilogue: C/D row = q*4+r (edge), col = n15; scatter-add by dst
#pragma unroll
  for (int mt = 0; mt < 2; ++mt) {
#pragma unroll
    for (int r = 0; r < 4; ++r) {
      int e = ebase + mt * 16 + q * 4 + r;
      int d = dst[e];
      float* ag = aggr + (size_t)d * HID;
#pragma unroll
      for (int nt = 0; nt < 4; ++nt)
        atomicAdd(ag + nt * 16 + n15, acc[mt][nt][r]);
    }
  }
}

// ---------------- update(t) [blocks 0..2047] + edgemlp(t+1) [blocks 2048..6143] ---
__global__ __launch_bounds__(256) void k_upd_em(
    float* __restrict__ v, const float* __restrict__ rw, const float* __restrict__ rb,
    float* __restrict__ aggr, const float* __restrict__ degf,
    const float* __restrict__ ear, const float* __restrict__ meanb,
    const float* __restrict__ invstd,
    const float* __restrict__ w1, const float* __restrict__ b1,
    const float* __restrict__ w2, const float* __restrict__ b2,
    float* __restrict__ h2, int do_em) {
  __shared__ float sh[4][HID];
  int g = threadIdx.x >> 6, lane = threadIdx.x & 63;
  if (blockIdx.x < NN / 4) {
    int n = blockIdx.x * 4 + g;
    int idx = n * HID + lane;
    sh[g][lane] = v[idx];
    __syncthreads();
    float inv = 1.f / fmaxf(degf[n], 1.f);
    float o = rb[lane] + aggr[idx] * inv;
    aggr[idx] = 0.f;                       // re-zero for next layer
#pragma unroll
    for (int h = 0; h < HID; ++h) o += sh[g][h] * rw[h * HID + lane];
    v[idx] = fmaxf(o, 0.f);
  } else {
    if (!do_em) return;
    int e = (blockIdx.x - NN / 4) * 4 + g;
    edgemlp_body(e, lane, g, sh, ear, meanb, invstd, w1, b1, w2, b2, h2);
  }
}

// ---------------- proj MLP ----------------
__global__ __launch_bounds__(256) void k_proj(const float* __restrict__ v,
    const float* __restrict__ w1, const float* __restrict__ b1,
    const float* __restrict__ w2, const float* __restrict__ b2,
    float* __restrict__ out) {
  __shared__ float h1s[4][HID];
  int g = threadIdx.x >> 6, lane = threadIdx.x & 63;
  int n = blockIdx.x * 4 + g;
  float a = b1[lane];
#pragma unroll
  for (int h = 0; h < HID; ++h) a += v[n * HID + h] * w1[h * HID + lane];
  h1s[g][lane] = fmaxf(a, 0.f);
  __syncthreads();
  if (lane < OUT_DIM) {
    float o = b2[lane];
#pragma unroll
    for (int h = 0; h < HID; ++h) o += h1s[g][h] * w2[h * OUT_DIM + lane];
    out[n * OUT_DIM + lane] = o;
  }
}

extern "C" void kernel_launch(void* const* d_in, const int* in_sizes, int n_in,
                              void* d_out, int out_size, void* d_ws, size_t ws_size,
                              hipStream_t stream) {
  const float* x        = (const float*)d_in[0];
  const float* ear      = (const float*)d_in[1];
  const float* lift_w1  = (const float*)d_in[2];
  const float* lift_b1  = (const float*)d_in[3];
  const float* lift_w2  = (const float*)d_in[4];
  const float* lift_b2  = (const float*)d_in[5];
  const float* root_w   = (const float*)d_in[6];
  const float* root_b   = (const float*)d_in[7];
  const float* kw1      = (const float*)d_in[8];
  const float* kb1      = (const float*)d_in[9];
  const float* kw2      = (const float*)d_in[10];
  const float* kb2      = (const float*)d_in[11];
  const float* kw3      = (const float*)d_in[12];
  const float* kb3      = (const float*)d_in[13];
  const float* pw1      = (const float*)d_in[14];
  const float* pb1      = (const float*)d_in[15];
  const float* pw2      = (const float*)d_in[16];
  const float* pb2      = (const float*)d_in[17];
  const int* edge_index = (const int*)d_in[18];
  const int* src = edge_index;
  const int* dst = edge_index + EE;
  float* out = (float*)d_out;

  float* ws     = (float*)d_ws;
  float* aggr   = ws;                          // NN*HID (memset with degf in one call)
  float* degf   = aggr + NN * HID;             // NN
  float* h2buf  = degf + NN;                   // EE*HID
  float* vbuf   = h2buf + EE * HID;            // NN*HID
  float* meanb  = vbuf + NN * HID;             // 72
  float* invstd = meanb + 72;                  // 72
  unsigned short* Bbf = (unsigned short*)(invstd + 72);  // TT*65*4096 bf16 (16B aligned)

  hipMemsetAsync(aggr, 0, (size_t)(NN * HID + NN) * sizeof(float), stream);
  k_pre<<<NN / 4 + 1024 + EE / 256 + N_GRAPHS, 256, 0, stream>>>(
      x, lift_w1, lift_b1, lift_w2, lift_b2, vbuf, kw3, kb3, Bbf,
      dst, degf, ear, meanb, invstd);
  k_em<<<EE / 4, 256, 0, stream>>>(ear, meanb, invstd,
      kw1, kb1, kw2, kb2, h2buf);

  for (int t = 0; t < TT; ++t) {
    k_msg<<<512, 256, 0, stream>>>(vbuf, h2buf, Bbf + (size_t)t * 65 * 4096,
                                   src, dst, aggr);
    int tt = (t < TT - 1) ? t + 1 : TT - 1;    // clamped (unused when do_em=0)
    k_upd_em<<<NN / 4 + EE / 4, 256, 0, stream>>>(
        vbuf, root_w + (size_t)t * HID * HID, root_b + (size_t)t * HID,
        aggr, degf, ear, meanb, invstd,
        kw1 + (size_t)tt * EDGE_DIM * HID, kb1 + (size_t)tt * HID,
        kw2 + (size_t)tt * HID * HID, kb2 + (size_t)tt * HID,
        h2buf, (t < TT - 1) ? 1 : 0);
  }
  k_proj<<<NN / 4, 256, 0, stream>>>(vbuf, pw1, pb1, pw2, pb2, out);
}